// Round 8
// baseline (213.819 us; speedup 1.0000x reference)
//
#include <hip/hip_runtime.h>
#include <stdint.h>

#define B_   4
#define N_   2048
#define C_   512
#define H_   4
#define HD_  128
#define BN_  (B_ * N_)
#define NIT_ 16
// exp(s/sqrt(128)) == exp2(s * SCALE_LOG2E)
#define SCALE_LOG2E 0.1275129727595311f

typedef __attribute__((ext_vector_type(8))) short  short8;
typedef __attribute__((ext_vector_type(4))) float  float4_t;
typedef __attribute__((ext_vector_type(8))) __bf16 bf16x8;

static __device__ __forceinline__ unsigned short f2bf(float f) {
  union { float f; uint32_t u; } v; v.f = f;
  uint32_t r = v.u + 0x7FFFu + ((v.u >> 16) & 1u);
  return (unsigned short)(r >> 16);
}

static __device__ __forceinline__ uint32_t cvtpk_bf16(float lo, float hi) {
  uint32_t r;
  asm("v_cvt_pk_bf16_f32 %0, %1, %2" : "=v"(r) : "v"(lo), "v"(hi));
  return r;
}

#if __has_builtin(__builtin_amdgcn_exp2f)
#define EXP2(x) __builtin_amdgcn_exp2f(x)
#else
#define EXP2(x) exp2f(x)
#endif

static __device__ __forceinline__ float4_t mfma16(short8 a, short8 b, float4_t c) {
  return __builtin_amdgcn_mfma_f32_16x16x32_bf16(
      __builtin_bit_cast(bf16x8, a), __builtin_bit_cast(bf16x8, b), c, 0, 0, 0);
}

#define GLOAD16(SRC, DST)                                               \
  __builtin_amdgcn_global_load_lds(                                     \
      (const __attribute__((address_space(1))) void*)(SRC),             \
      (__attribute__((address_space(3))) void*)(DST), 16, 0, 0)

// ---- kernel 1: per-token norm/var/sum + normalized bf16 x ------------------
__global__ __launch_bounds__(256) void k_stats(
    const float* __restrict__ x, unsigned short* __restrict__ xnq,
    float* __restrict__ diff, float* __restrict__ toksum) {
  int tok  = blockIdx.x * 4 + (threadIdx.x >> 6);
  int lane = threadIdx.x & 63;
  const float* xr = x + (size_t)tok * C_;
  float4_t a = *(const float4_t*)(xr + lane * 8);
  float4_t b = *(const float4_t*)(xr + lane * 8 + 4);
  float s = 0.f, ss = 0.f;
#pragma unroll
  for (int j = 0; j < 4; ++j) {
    s  += a[j] + b[j];
    ss += a[j] * a[j] + b[j] * b[j];
  }
#pragma unroll
  for (int o = 1; o < 64; o <<= 1) {
    s  += __shfl_xor(s, o);
    ss += __shfl_xor(ss, o);
  }
  float rn = 1.f / fmaxf(sqrtf(ss), 1e-12f);
  short8 o8;
#pragma unroll
  for (int j = 0; j < 4; ++j) {
    o8[j]     = (short)f2bf(a[j] * rn);
    o8[j + 4] = (short)f2bf(b[j] * rn);
  }
  *(short8*)(xnq + (size_t)tok * C_ + lane * 8) = o8;
  if (lane == 0) {
    diff[tok]   = (ss - s * s * (1.f / C_)) * (1.f / (C_ - 1));  // ddof=1
    toksum[tok] = s;
  }
}

// ---- kernel 1b: per-head transposed bf16 V ---------------------------------
// xvT[bh][d] row of N ushorts, 64-key segments of 8 blocks; block lg (in
// order, NO physical XOR) holds keys 32*(lg>>2)+4*(lg&3)+16*(e>>2)+(e&3)
// (MFMA A k-slot order). k_attn applies its own slot XOR when staging.
__global__ __launch_bounds__(256) void k_transpose(
    const float* __restrict__ x, unsigned short* __restrict__ xvT) {
  __shared__ float tr[HD_][65];
  int bh = blockIdx.x & 15, nt = blockIdx.x >> 4;
  int b = bh >> 2, h = bh & 3;
  int n0 = nt * 64, c0 = h * HD_;
  int t = threadIdx.x;
  int dm = (t & 31) * 4;
  int nr = t >> 5;
#pragma unroll
  for (int p = 0; p < 8; ++p) {
    int n = p * 8 + nr;
    float4_t v = *(const float4_t*)(x + ((size_t)(b * N_ + n0 + n)) * C_ + c0 + dm);
#pragma unroll
    for (int k = 0; k < 4; ++k) tr[dm + k][n] = v[k];
  }
  __syncthreads();
#pragma unroll
  for (int p4 = 0; p4 < 4; ++p4) {
    int c = p4 * 256 + t;
    int d = c >> 3, lg = c & 7;
    int kbase = 32 * (lg >> 2) + 4 * (lg & 3);
    short8 o8;
#pragma unroll
    for (int e = 0; e < 8; ++e)
      o8[e] = (short)f2bf(tr[d][kbase + 16 * (e >> 2) + (e & 3)]);
    *(short8*)(xvT + ((size_t)(bh * HD_ + d)) * N_ + n0 + lg * 8) = o8;
  }
}

// ---- kernel 2: global diff mean/std + per-batch gate -----------------------
__global__ __launch_bounds__(256) void k_finalize(
    const float* __restrict__ diff, const float* __restrict__ toksum,
    const float* __restrict__ gw, const float* __restrict__ gb,
    float* __restrict__ stats) {
  __shared__ float sh[4][8];
  int t = threadIdx.x, l = t & 63, w = t >> 6;
  float s1 = 0.f, s2 = 0.f;
  for (int i = t; i < BN_; i += 256) { float d = diff[i]; s1 += d; s2 += d * d; }
  float bs0 = 0.f, bs1 = 0.f, bs2 = 0.f, bs3 = 0.f;
  for (int i = t; i < N_; i += 256) {
    bs0 += toksum[i];          bs1 += toksum[N_ + i];
    bs2 += toksum[2 * N_ + i]; bs3 += toksum[3 * N_ + i];
  }
#pragma unroll
  for (int o = 1; o < 64; o <<= 1) {
    s1 += __shfl_xor(s1, o);  s2 += __shfl_xor(s2, o);
    bs0 += __shfl_xor(bs0, o); bs1 += __shfl_xor(bs1, o);
    bs2 += __shfl_xor(bs2, o); bs3 += __shfl_xor(bs3, o);
  }
  if (l == 0) {
    sh[w][0] = s1; sh[w][1] = s2;
    sh[w][2] = bs0; sh[w][3] = bs1; sh[w][4] = bs2; sh[w][5] = bs3;
  }
  __syncthreads();
  if (t == 0) {
    float S1 = sh[0][0] + sh[1][0] + sh[2][0] + sh[3][0];
    float S2 = sh[0][1] + sh[1][1] + sh[2][1] + sh[3][1];
    float mean = S1 / (float)BN_;
    float var  = (S2 - S1 * S1 / (float)BN_) / (float)(BN_ - 1);
    float rstd = 1.f / (sqrtf(var) + 1e-6f);
    stats[0] = mean; stats[1] = rstd;
    float w00 = gw[0], bb = gb[0];
#pragma unroll
    for (int q = 0; q < 4; ++q) {
      float bsum = sh[0][2 + q] + sh[1][2 + q] + sh[2][2 + q] + sh[3][2 + q];
      float gi = bsum / (float)(N_ * C_);
      stats[2 + q] = 1.f / (1.f + __expf(-(gi * w00 + bb)));
    }
  }
}

// ---- kernel 3: fused flash attention + edge/gate epilogue ------------------
// grid 256 (1 block/CU) x 512 thr (8 waves = 2/SIMD; co-residency caps
// VGPR+AGPR at 256/wave -- R5/R6 spilled because transient live set pushed
// demand to ~290).  This version phases the inner loop to fit:
//   per iter: for ks2 in {0,1}: { kf[4] (16 regs); for qs: p(4 regs) -> exp
//   -> pfq[qs] } ; then PV.  Peak ~= 128(acc)+64(qf)+21(addr)+38(transient).
__global__ __launch_bounds__(512) void k_attn(
    const float* __restrict__ x, const unsigned short* __restrict__ xnq,
    const unsigned short* __restrict__ xvT, const float* __restrict__ diff,
    const float* __restrict__ stats, float* __restrict__ out) {
  extern __shared__ unsigned char smraw[];
  int i  = blockIdx.x;
  int bh = ((i & 7) << 1) | ((i >> 3) & 1);   // XCD-affine
  int qt = i >> 4;
  int b = bh >> 2, h = bh & 3, c0 = h * HD_;
  int tid = threadIdx.x, w = tid >> 6, l = tid & 63;
  int ks = w & 3, qh = w >> 2;
  int g = l >> 4, r = l & 15;
  int q0 = qt * 128 + qh * 64;

  // Q fragments: 4 q-subtiles x 4 channel-slices (B-operand), 64 VGPRs
  short8 qf[4][4];
  const unsigned short* qbase = xnq + ((size_t)(b * N_ + q0)) * C_ + c0;
#pragma unroll
  for (int qs = 0; qs < 4; ++qs)
#pragma unroll
    for (int cs = 0; cs < 4; ++cs)
      qf[qs][cs] = *(const short8*)(qbase + (size_t)(qs * 16 + r) * C_ + cs * 32 + g * 8);

  // staging source offsets (ushort elements), advanced incrementally
  uint32_t koff[4], voff[4];
  const unsigned short* kqbase = xnq + (size_t)b * N_ * C_ + c0;
  const unsigned short* vgbase = xvT + (size_t)bh * HD_ * N_;
#pragma unroll
  for (int jj = 0; jj < 4; ++jj) {
    int j   = w * 4 + jj;
    int row = 4 * j + (l >> 4);
    int cb  = (l & 15) ^ (row & 15);
    koff[jj] = (uint32_t)(((row >> 5) * 512 + (row & 31)) * C_ + cb * 8);
    int d   = row;
    int ksg = (l & 15) ^ (d & 15);
    voff[jj] = (uint32_t)(d * N_ + (ksg >> 2) * 512 + (ksg & 3) * 8);
  }

  // LDS read bases (byte offsets into smraw)
  int kaddr[4];
#pragma unroll
  for (int cs = 0; cs < 4; ++cs)
    kaddr[cs] = (ks * 32 + r) * 256 + (((g + cs * 4) ^ r) * 16);
  int vaddr = 65536 + r * 256 + (((ks * 4 + g) ^ r) * 16);

  float4_t acc[8][4];
  float ls[4] = {0.f, 0.f, 0.f, 0.f};
#pragma unroll
  for (int dt = 0; dt < 8; ++dt)
#pragma unroll
    for (int qs = 0; qs < 4; ++qs) acc[dt][qs] = (float4_t){0.f, 0.f, 0.f, 0.f};

  auto stage = [&](int cb) {
#pragma unroll
    for (int jj = 0; jj < 4; ++jj)
      GLOAD16(kqbase + koff[jj], smraw + cb * 32768 + (w * 4 + jj) * 1024);
#pragma unroll
    for (int jj = 0; jj < 4; ++jj)
      GLOAD16(vgbase + voff[jj], smraw + 65536 + cb * 32768 + (w * 4 + jj) * 1024);
  };
  auto advance = [&]() {
#pragma unroll
    for (int jj = 0; jj < 4; ++jj) { koff[jj] += 32 * C_; voff[jj] += 32; }
  };

  stage(0);
  advance();
  __syncthreads();

#pragma unroll 2
  for (int it = 0; it < NIT_; ++it) {
    int cb = it & 1;
    if (it + 1 < NIT_) { stage(cb ^ 1); advance(); }

    const char* smb = (const char*)smraw;
    union { short8 s8; uint32_t u[4]; } pfq[4];

    // QK^T + softmax, phased: per ks2 hold kf[4] (16 regs); per qs a single
    // p (4 regs) -> exp2 -> pack.  Keeps transient live-set minimal.
#pragma unroll
    for (int ks2 = 0; ks2 < 2; ++ks2) {
      short8 kf[4];
#pragma unroll
      for (int cs = 0; cs < 4; ++cs)
        kf[cs] = *(const short8*)(smb + cb * 32768 + ks2 * 4096 + kaddr[cs]);
      __builtin_amdgcn_s_setprio(1);
#pragma unroll
      for (int qs = 0; qs < 4; ++qs) {
        float4_t p = (float4_t){0.f, 0.f, 0.f, 0.f};
#pragma unroll
        for (int cs = 0; cs < 4; ++cs)
          p = mfma16(kf[cs], qf[qs][cs], p);
        float e0 = EXP2(p[0] * SCALE_LOG2E);
        float e1 = EXP2(p[1] * SCALE_LOG2E);
        float e2 = EXP2(p[2] * SCALE_LOG2E);
        float e3 = EXP2(p[3] * SCALE_LOG2E);
        ls[qs] += (e0 + e1) + (e2 + e3);
        pfq[qs].u[ks2 * 2 + 0] = cvtpk_bf16(e0, e1);
        pfq[qs].u[ks2 * 2 + 1] = cvtpk_bf16(e2, e3);
      }
      __builtin_amdgcn_s_setprio(0);
    }

    // PV: O^T += V^T(32-key slice) * P^T
    __builtin_amdgcn_s_setprio(1);
#pragma unroll
    for (int dt = 0; dt < 8; ++dt) {
      short8 vf = *(const short8*)(smb + cb * 32768 + dt * 4096 + vaddr);
#pragma unroll
      for (int qs = 0; qs < 4; ++qs)
        acc[dt][qs] = mfma16(vf, pfq[qs].s8, acc[dt][qs]);
    }
    __builtin_amdgcn_s_setprio(0);
    __syncthreads();
  }

  // ---- epilogue: ls cross-lane + cross-ks; O cross-ks in 4 dt-rounds ------
#pragma unroll
  for (int qs = 0; qs < 4; ++qs) {
    ls[qs] += __shfl_xor(ls[qs], 16);
    ls[qs] += __shfl_xor(ls[qs], 32);
  }
  float* lsx = (float*)smraw;
  if (l < 16) {
#pragma unroll
    for (int qs = 0; qs < 4; ++qs) lsx[(w * 4 + qs) * 16 + l] = ls[qs];
  }
  __syncthreads();
  float lst[4];
#pragma unroll
  for (int qs = 0; qs < 4; ++qs)
    lst[qs] = lsx[((qh * 4 + 0) * 4 + qs) * 16 + r] + lsx[((qh * 4 + 1) * 4 + qs) * 16 + r] +
              lsx[((qh * 4 + 2) * 4 + qs) * 16 + r] + lsx[((qh * 4 + 3) * 4 + qs) * 16 + r];

  float mean = stats[0], rstd = stats[1], gate = stats[2 + b];
  float fq[4];
#pragma unroll
  for (int qs = 0; qs < 4; ++qs) {
    int q = q0 + qs * 16 + r;
    float dv = diff[b * N_ + q];
    float em = 1.f / (1.f + __expf(-(dv - mean) * rstd));
    fq[qs] = gate * (1.f + 0.5f * em) / lst[qs];
  }

  float4_t* ex = (float4_t*)(smraw + 4096);
#pragma unroll
  for (int rr = 0; rr < 4; ++rr) {
    __syncthreads();
#pragma unroll
    for (int dd = 0; dd < 2; ++dd)
#pragma unroll
      for (int qs = 0; qs < 4; ++qs)
        ex[((w * 2 + dd) * 4 + qs) * 64 + l] = acc[rr * 2 + dd][qs];
    __syncthreads();
    if (ks == rr) {
#pragma unroll
      for (int dd = 0; dd < 2; ++dd) {
        int dt = rr * 2 + dd;
#pragma unroll
        for (int qs = 0; qs < 4; ++qs) {
          float4_t sum = ex[(((qh * 4 + 0) * 2 + dd) * 4 + qs) * 64 + l];
#pragma unroll
          for (int k2 = 1; k2 < 4; ++k2) {
            float4_t o = ex[(((qh * 4 + k2) * 2 + dd) * 4 + qs) * 64 + l];
#pragma unroll
            for (int j = 0; j < 4; ++j) sum[j] += o[j];
          }
          int q = q0 + qs * 16 + r;
          int dcol = c0 + dt * 16 + g * 4;   // C/D: row = 4g+j, col = r
          const float* xr2 = x + ((size_t)(b * N_ + q)) * C_ + dcol;
          float* orow = out + ((size_t)(b * N_ + q)) * C_ + dcol;
          float4_t xin = *(const float4_t*)xr2;
          float4_t o;
#pragma unroll
          for (int j = 0; j < 4; ++j) o[j] = xin[j] + fq[qs] * sum[j];
          *(float4_t*)orow = o;
        }
      }
    }
  }
}

extern "C" void kernel_launch(void* const* d_in, const int* in_sizes, int n_in,
                              void* d_out, int out_size, void* d_ws, size_t ws_size,
                              hipStream_t stream) {
  (void)in_sizes; (void)n_in; (void)out_size; (void)ws_size;
  const float* x  = (const float*)d_in[0];
  const float* gw = (const float*)d_in[1];
  const float* gb = (const float*)d_in[2];
  float* out = (float*)d_out;
  // ws layout: xnq bf16 [8192][512] | xvT bf16 [16][128][2048] | diff | toksum | stats
  unsigned short* xnq = (unsigned short*)d_ws;
  unsigned short* xvT = xnq + (size_t)BN_ * C_;
  float* diff   = (float*)(xvT + (size_t)BN_ * C_);
  float* toksum = diff + BN_;
  float* stats  = toksum + BN_;
  hipFuncSetAttribute((const void*)k_attn,
                      hipFuncAttributeMaxDynamicSharedMemorySize, 131072);
  hipLaunchKernelGGL(k_stats, dim3(BN_ / 4), dim3(256), 0, stream, x, xnq, diff, toksum);
  hipLaunchKernelGGL(k_transpose, dim3(512), dim3(256), 0, stream, x, xvT);
  hipLaunchKernelGGL(k_finalize, dim3(1), dim3(256), 0, stream, diff, toksum, gw, gb, stats);
  hipLaunchKernelGGL(k_attn, dim3(256), dim3(512), 131072, stream,
                     x, xnq, xvT, diff, stats, out);
}

// Round 9
// 182.387 us; speedup vs baseline: 1.1723x; 1.1723x over previous
//
#include <hip/hip_runtime.h>
#include <stdint.h>

#define B_   4
#define N_   2048
#define C_   512
#define H_   4
#define HD_  128
#define BN_  (B_ * N_)
#define NIT_ 16
// exp(s/sqrt(128)) == exp2(s * SCALE_LOG2E)
#define SCALE_LOG2E 0.1275129727595311f

typedef __attribute__((ext_vector_type(8))) short  short8;
typedef __attribute__((ext_vector_type(4))) float  float4_t;
typedef __attribute__((ext_vector_type(8))) __bf16 bf16x8;

static __device__ __forceinline__ unsigned short f2bf(float f) {
  union { float f; uint32_t u; } v; v.f = f;
  uint32_t r = v.u + 0x7FFFu + ((v.u >> 16) & 1u);
  return (unsigned short)(r >> 16);
}

static __device__ __forceinline__ uint32_t cvtpk_bf16(float lo, float hi) {
  uint32_t r;
  asm("v_cvt_pk_bf16_f32 %0, %1, %2" : "=v"(r) : "v"(lo), "v"(hi));
  return r;
}

#if __has_builtin(__builtin_amdgcn_exp2f)
#define EXP2(x) __builtin_amdgcn_exp2f(x)
#else
#define EXP2(x) exp2f(x)
#endif

static __device__ __forceinline__ float4_t mfma16(short8 a, short8 b, float4_t c) {
  return __builtin_amdgcn_mfma_f32_16x16x32_bf16(
      __builtin_bit_cast(bf16x8, a), __builtin_bit_cast(bf16x8, b), c, 0, 0, 0);
}

#define GLOAD16(SRC, DST)                                               \
  __builtin_amdgcn_global_load_lds(                                     \
      (const __attribute__((address_space(1))) void*)(SRC),             \
      (__attribute__((address_space(3))) void*)(DST), 16, 0, 0)

// ---- kernel 1: per-token norm/var/sum + normalized bf16 x ------------------
__global__ __launch_bounds__(256) void k_stats(
    const float* __restrict__ x, unsigned short* __restrict__ xnq,
    float* __restrict__ diff, float* __restrict__ toksum) {
  int tok  = blockIdx.x * 4 + (threadIdx.x >> 6);
  int lane = threadIdx.x & 63;
  const float* xr = x + (size_t)tok * C_;
  float4_t a = *(const float4_t*)(xr + lane * 8);
  float4_t b = *(const float4_t*)(xr + lane * 8 + 4);
  float s = 0.f, ss = 0.f;
#pragma unroll
  for (int j = 0; j < 4; ++j) {
    s  += a[j] + b[j];
    ss += a[j] * a[j] + b[j] * b[j];
  }
#pragma unroll
  for (int o = 1; o < 64; o <<= 1) {
    s  += __shfl_xor(s, o);
    ss += __shfl_xor(ss, o);
  }
  float rn = 1.f / fmaxf(sqrtf(ss), 1e-12f);
  short8 o8;
#pragma unroll
  for (int j = 0; j < 4; ++j) {
    o8[j]     = (short)f2bf(a[j] * rn);
    o8[j + 4] = (short)f2bf(b[j] * rn);
  }
  *(short8*)(xnq + (size_t)tok * C_ + lane * 8) = o8;
  if (lane == 0) {
    diff[tok]   = (ss - s * s * (1.f / C_)) * (1.f / (C_ - 1));  // ddof=1
    toksum[tok] = s;
  }
}

// ---- kernel 1b: per-head transposed bf16 V ---------------------------------
// xvT[bh][d] row of N ushorts, 64-key segments of 8 blocks; block lg (in
// order, NO physical XOR) holds keys 32*(lg>>2)+4*(lg&3)+16*(e>>2)+(e&3)
// (MFMA A k-slot order). k_attn applies its own slot XOR when staging.
__global__ __launch_bounds__(256) void k_transpose(
    const float* __restrict__ x, unsigned short* __restrict__ xvT) {
  __shared__ float tr[HD_][65];
  int bh = blockIdx.x & 15, nt = blockIdx.x >> 4;
  int b = bh >> 2, h = bh & 3;
  int n0 = nt * 64, c0 = h * HD_;
  int t = threadIdx.x;
  int dm = (t & 31) * 4;
  int nr = t >> 5;
#pragma unroll
  for (int p = 0; p < 8; ++p) {
    int n = p * 8 + nr;
    float4_t v = *(const float4_t*)(x + ((size_t)(b * N_ + n0 + n)) * C_ + c0 + dm);
#pragma unroll
    for (int k = 0; k < 4; ++k) tr[dm + k][n] = v[k];
  }
  __syncthreads();
#pragma unroll
  for (int p4 = 0; p4 < 4; ++p4) {
    int c = p4 * 256 + t;
    int d = c >> 3, lg = c & 7;
    int kbase = 32 * (lg >> 2) + 4 * (lg & 3);
    short8 o8;
#pragma unroll
    for (int e = 0; e < 8; ++e)
      o8[e] = (short)f2bf(tr[d][kbase + 16 * (e >> 2) + (e & 3)]);
    *(short8*)(xvT + ((size_t)(bh * HD_ + d)) * N_ + n0 + lg * 8) = o8;
  }
}

// ---- kernel 2: global diff mean/std + per-batch gate -----------------------
__global__ __launch_bounds__(256) void k_finalize(
    const float* __restrict__ diff, const float* __restrict__ toksum,
    const float* __restrict__ gw, const float* __restrict__ gb,
    float* __restrict__ stats) {
  __shared__ float sh[4][8];
  int t = threadIdx.x, l = t & 63, w = t >> 6;
  float s1 = 0.f, s2 = 0.f;
  for (int i = t; i < BN_; i += 256) { float d = diff[i]; s1 += d; s2 += d * d; }
  float bs0 = 0.f, bs1 = 0.f, bs2 = 0.f, bs3 = 0.f;
  for (int i = t; i < N_; i += 256) {
    bs0 += toksum[i];          bs1 += toksum[N_ + i];
    bs2 += toksum[2 * N_ + i]; bs3 += toksum[3 * N_ + i];
  }
#pragma unroll
  for (int o = 1; o < 64; o <<= 1) {
    s1 += __shfl_xor(s1, o);  s2 += __shfl_xor(s2, o);
    bs0 += __shfl_xor(bs0, o); bs1 += __shfl_xor(bs1, o);
    bs2 += __shfl_xor(bs2, o); bs3 += __shfl_xor(bs3, o);
  }
  if (l == 0) {
    sh[w][0] = s1; sh[w][1] = s2;
    sh[w][2] = bs0; sh[w][3] = bs1; sh[w][4] = bs2; sh[w][5] = bs3;
  }
  __syncthreads();
  if (t == 0) {
    float S1 = sh[0][0] + sh[1][0] + sh[2][0] + sh[3][0];
    float S2 = sh[0][1] + sh[1][1] + sh[2][1] + sh[3][1];
    float mean = S1 / (float)BN_;
    float var  = (S2 - S1 * S1 / (float)BN_) / (float)(BN_ - 1);
    float rstd = 1.f / (sqrtf(var) + 1e-6f);
    stats[0] = mean; stats[1] = rstd;
    float w00 = gw[0], bb = gb[0];
#pragma unroll
    for (int q = 0; q < 4; ++q) {
      float bsum = sh[0][2 + q] + sh[1][2 + q] + sh[2][2 + q] + sh[3][2 + q];
      float gi = bsum / (float)(N_ * C_);
      stats[2 + q] = 1.f / (1.f + __expf(-(gi * w00 + bb)));
    }
  }
}

// ---- kernel 3: fused flash attention + edge/gate epilogue ------------------
// grid 256 (1 block/CU) x 512 thr (8 waves = 2/SIMD).
// R5-R7 lesson: hipcc's allocator picks its own occupancy target (-> 128 arch
// VGPR cap) and spills ~35 regs/iter (= 300-376MB scratch HBM traffic) no
// matter what __launch_bounds__ says.  amdgpu_waves_per_eu(2,2) pins the
// target at 2 waves/EU = 1024 regs/wave budget; demand is ~265 (128 acc +
// ~137 arch), so spills should vanish entirely.
__global__ __attribute__((amdgpu_flat_work_group_size(512, 512)))
__attribute__((amdgpu_waves_per_eu(2, 2))) void k_attn(
    const float* __restrict__ x, const unsigned short* __restrict__ xnq,
    const unsigned short* __restrict__ xvT, const float* __restrict__ diff,
    const float* __restrict__ stats, float* __restrict__ out) {
  extern __shared__ unsigned char smraw[];
  int i  = blockIdx.x;
  int bh = ((i & 7) << 1) | ((i >> 3) & 1);   // XCD-affine
  int qt = i >> 4;
  int b = bh >> 2, h = bh & 3, c0 = h * HD_;
  int tid = threadIdx.x, w = tid >> 6, l = tid & 63;
  int ks = w & 3, qh = w >> 2;
  int g = l >> 4, r = l & 15;
  int q0 = qt * 128 + qh * 64;

  // Q fragments: 4 q-subtiles x 4 channel-slices (B-operand), 64 VGPRs
  short8 qf[4][4];
  const unsigned short* qbase = xnq + ((size_t)(b * N_ + q0)) * C_ + c0;
#pragma unroll
  for (int qs = 0; qs < 4; ++qs)
#pragma unroll
    for (int cs = 0; cs < 4; ++cs)
      qf[qs][cs] = *(const short8*)(qbase + (size_t)(qs * 16 + r) * C_ + cs * 32 + g * 8);

  // staging source offsets (ushort elements), advanced incrementally
  uint32_t koff[4], voff[4];
  const unsigned short* kqbase = xnq + (size_t)b * N_ * C_ + c0;
  const unsigned short* vgbase = xvT + (size_t)bh * HD_ * N_;
#pragma unroll
  for (int jj = 0; jj < 4; ++jj) {
    int j   = w * 4 + jj;
    int row = 4 * j + (l >> 4);
    int cb  = (l & 15) ^ (row & 15);
    koff[jj] = (uint32_t)(((row >> 5) * 512 + (row & 31)) * C_ + cb * 8);
    int d   = row;
    int ksg = (l & 15) ^ (d & 15);
    voff[jj] = (uint32_t)(d * N_ + (ksg >> 2) * 512 + (ksg & 3) * 8);
  }

  // LDS read bases (byte offsets into smraw)
  int kaddr[4];
#pragma unroll
  for (int cs = 0; cs < 4; ++cs)
    kaddr[cs] = (ks * 32 + r) * 256 + (((g + cs * 4) ^ r) * 16);
  int vaddr = 65536 + r * 256 + (((ks * 4 + g) ^ r) * 16);

  float4_t acc[8][4];
  float ls[4] = {0.f, 0.f, 0.f, 0.f};
#pragma unroll
  for (int dt = 0; dt < 8; ++dt)
#pragma unroll
    for (int qs = 0; qs < 4; ++qs) acc[dt][qs] = (float4_t){0.f, 0.f, 0.f, 0.f};

  auto stage = [&](int cb) {
#pragma unroll
    for (int jj = 0; jj < 4; ++jj)
      GLOAD16(kqbase + koff[jj], smraw + cb * 32768 + (w * 4 + jj) * 1024);
#pragma unroll
    for (int jj = 0; jj < 4; ++jj)
      GLOAD16(vgbase + voff[jj], smraw + 65536 + cb * 32768 + (w * 4 + jj) * 1024);
  };
  auto advance = [&]() {
#pragma unroll
    for (int jj = 0; jj < 4; ++jj) { koff[jj] += 32 * C_; voff[jj] += 32; }
  };

  stage(0);
  advance();
  __syncthreads();

#pragma unroll 2
  for (int it = 0; it < NIT_; ++it) {
    int cb = it & 1;
    if (it + 1 < NIT_) { stage(cb ^ 1); advance(); }

    const char* smb = (const char*)smraw;
    union { short8 s8; uint32_t u[4]; } pfq[4];

    // QK^T + softmax, phased: per ks2 hold kf[4] (16 regs); per qs a single
    // p (4 regs) -> exp2 -> pack.  Keeps transient live-set minimal.
#pragma unroll
    for (int ks2 = 0; ks2 < 2; ++ks2) {
      short8 kf[4];
#pragma unroll
      for (int cs = 0; cs < 4; ++cs)
        kf[cs] = *(const short8*)(smb + cb * 32768 + ks2 * 4096 + kaddr[cs]);
      __builtin_amdgcn_s_setprio(1);
#pragma unroll
      for (int qs = 0; qs < 4; ++qs) {
        float4_t p = (float4_t){0.f, 0.f, 0.f, 0.f};
#pragma unroll
        for (int cs = 0; cs < 4; ++cs)
          p = mfma16(kf[cs], qf[qs][cs], p);
        float e0 = EXP2(p[0] * SCALE_LOG2E);
        float e1 = EXP2(p[1] * SCALE_LOG2E);
        float e2 = EXP2(p[2] * SCALE_LOG2E);
        float e3 = EXP2(p[3] * SCALE_LOG2E);
        ls[qs] += (e0 + e1) + (e2 + e3);
        pfq[qs].u[ks2 * 2 + 0] = cvtpk_bf16(e0, e1);
        pfq[qs].u[ks2 * 2 + 1] = cvtpk_bf16(e2, e3);
      }
      __builtin_amdgcn_s_setprio(0);
    }

    // PV: O^T += V^T(32-key slice) * P^T
    __builtin_amdgcn_s_setprio(1);
#pragma unroll
    for (int dt = 0; dt < 8; ++dt) {
      short8 vf = *(const short8*)(smb + cb * 32768 + dt * 4096 + vaddr);
#pragma unroll
      for (int qs = 0; qs < 4; ++qs)
        acc[dt][qs] = mfma16(vf, pfq[qs].s8, acc[dt][qs]);
    }
    __builtin_amdgcn_s_setprio(0);
    __syncthreads();
  }

  // ---- epilogue: ls cross-lane + cross-ks; O cross-ks in 4 dt-rounds ------
#pragma unroll
  for (int qs = 0; qs < 4; ++qs) {
    ls[qs] += __shfl_xor(ls[qs], 16);
    ls[qs] += __shfl_xor(ls[qs], 32);
  }
  float* lsx = (float*)smraw;
  if (l < 16) {
#pragma unroll
    for (int qs = 0; qs < 4; ++qs) lsx[(w * 4 + qs) * 16 + l] = ls[qs];
  }
  __syncthreads();
  float lst[4];
#pragma unroll
  for (int qs = 0; qs < 4; ++qs)
    lst[qs] = lsx[((qh * 4 + 0) * 4 + qs) * 16 + r] + lsx[((qh * 4 + 1) * 4 + qs) * 16 + r] +
              lsx[((qh * 4 + 2) * 4 + qs) * 16 + r] + lsx[((qh * 4 + 3) * 4 + qs) * 16 + r];

  float mean = stats[0], rstd = stats[1], gate = stats[2 + b];
  float fq[4];
#pragma unroll
  for (int qs = 0; qs < 4; ++qs) {
    int q = q0 + qs * 16 + r;
    float dv = diff[b * N_ + q];
    float em = 1.f / (1.f + __expf(-(dv - mean) * rstd));
    fq[qs] = gate * (1.f + 0.5f * em) / lst[qs];
  }

  float4_t* ex = (float4_t*)(smraw + 4096);
#pragma unroll
  for (int rr = 0; rr < 4; ++rr) {
    __syncthreads();
#pragma unroll
    for (int dd = 0; dd < 2; ++dd)
#pragma unroll
      for (int qs = 0; qs < 4; ++qs)
        ex[((w * 2 + dd) * 4 + qs) * 64 + l] = acc[rr * 2 + dd][qs];
    __syncthreads();
    if (ks == rr) {
#pragma unroll
      for (int dd = 0; dd < 2; ++dd) {
        int dt = rr * 2 + dd;
#pragma unroll
        for (int qs = 0; qs < 4; ++qs) {
          float4_t sum = ex[(((qh * 4 + 0) * 2 + dd) * 4 + qs) * 64 + l];
#pragma unroll
          for (int k2 = 1; k2 < 4; ++k2) {
            float4_t o = ex[(((qh * 4 + k2) * 2 + dd) * 4 + qs) * 64 + l];
#pragma unroll
            for (int j = 0; j < 4; ++j) sum[j] += o[j];
          }
          int q = q0 + qs * 16 + r;
          int dcol = c0 + dt * 16 + g * 4;   // C/D: row = 4g+j, col = r
          const float* xr2 = x + ((size_t)(b * N_ + q)) * C_ + dcol;
          float* orow = out + ((size_t)(b * N_ + q)) * C_ + dcol;
          float4_t xin = *(const float4_t*)xr2;
          float4_t o;
#pragma unroll
          for (int j = 0; j < 4; ++j) o[j] = xin[j] + fq[qs] * sum[j];
          *(float4_t*)orow = o;
        }
      }
    }
  }
}

extern "C" void kernel_launch(void* const* d_in, const int* in_sizes, int n_in,
                              void* d_out, int out_size, void* d_ws, size_t ws_size,
                              hipStream_t stream) {
  (void)in_sizes; (void)n_in; (void)out_size; (void)ws_size;
  const float* x  = (const float*)d_in[0];
  const float* gw = (const float*)d_in[1];
  const float* gb = (const float*)d_in[2];
  float* out = (float*)d_out;
  // ws layout: xnq bf16 [8192][512] | xvT bf16 [16][128][2048] | diff | toksum | stats
  unsigned short* xnq = (unsigned short*)d_ws;
  unsigned short* xvT = xnq + (size_t)BN_ * C_;
  float* diff   = (float*)(xvT + (size_t)BN_ * C_);
  float* toksum = diff + BN_;
  float* stats  = toksum + BN_;
  hipFuncSetAttribute((const void*)k_attn,
                      hipFuncAttributeMaxDynamicSharedMemorySize, 131072);
  hipLaunchKernelGGL(k_stats, dim3(BN_ / 4), dim3(256), 0, stream, x, xnq, diff, toksum);
  hipLaunchKernelGGL(k_transpose, dim3(512), dim3(256), 0, stream, x, xvT);
  hipLaunchKernelGGL(k_finalize, dim3(1), dim3(256), 0, stream, diff, toksum, gw, gb, stats);
  hipLaunchKernelGGL(k_attn, dim3(256), dim3(512), 131072, stream,
                     x, xnq, xvT, diff, stats, out);
}

// Round 10
// 94.735 us; speedup vs baseline: 2.2570x; 1.9252x over previous
//
#include <hip/hip_runtime.h>
#include <stdint.h>

#define B_   4
#define N_   2048
#define C_   512
#define H_   4
#define HD_  128
#define BN_  (B_ * N_)
#define NIT_ 16
// exp(s/sqrt(128)) == exp2(s * SCALE_LOG2E)
#define SCALE_LOG2E 0.1275129727595311f

typedef __attribute__((ext_vector_type(8))) short  short8;
typedef __attribute__((ext_vector_type(4))) float  float4_t;
typedef __attribute__((ext_vector_type(8))) __bf16 bf16x8;

static __device__ __forceinline__ unsigned short f2bf(float f) {
  union { float f; uint32_t u; } v; v.f = f;
  uint32_t r = v.u + 0x7FFFu + ((v.u >> 16) & 1u);
  return (unsigned short)(r >> 16);
}

static __device__ __forceinline__ uint32_t cvtpk_bf16(float lo, float hi) {
  uint32_t r;
  asm("v_cvt_pk_bf16_f32 %0, %1, %2" : "=v"(r) : "v"(lo), "v"(hi));
  return r;
}

#if __has_builtin(__builtin_amdgcn_exp2f)
#define EXP2(x) __builtin_amdgcn_exp2f(x)
#else
#define EXP2(x) exp2f(x)
#endif

static __device__ __forceinline__ float4_t mfma16(short8 a, short8 b, float4_t c) {
  return __builtin_amdgcn_mfma_f32_16x16x32_bf16(
      __builtin_bit_cast(bf16x8, a), __builtin_bit_cast(bf16x8, b), c, 0, 0, 0);
}

#define GLOAD16(SRC, DST)                                               \
  __builtin_amdgcn_global_load_lds(                                     \
      (const __attribute__((address_space(1))) void*)(SRC),             \
      (__attribute__((address_space(3))) void*)(DST), 16, 0, 0)

// ---- kernel 1: per-token norm/var/sum + normalized bf16 x ------------------
__global__ __launch_bounds__(256) void k_stats(
    const float* __restrict__ x, unsigned short* __restrict__ xnq,
    float* __restrict__ diff, float* __restrict__ toksum) {
  int tok  = blockIdx.x * 4 + (threadIdx.x >> 6);
  int lane = threadIdx.x & 63;
  const float* xr = x + (size_t)tok * C_;
  float4_t a = *(const float4_t*)(xr + lane * 8);
  float4_t b = *(const float4_t*)(xr + lane * 8 + 4);
  float s = 0.f, ss = 0.f;
#pragma unroll
  for (int j = 0; j < 4; ++j) {
    s  += a[j] + b[j];
    ss += a[j] * a[j] + b[j] * b[j];
  }
#pragma unroll
  for (int o = 1; o < 64; o <<= 1) {
    s  += __shfl_xor(s, o);
    ss += __shfl_xor(ss, o);
  }
  float rn = 1.f / fmaxf(sqrtf(ss), 1e-12f);
  short8 o8;
#pragma unroll
  for (int j = 0; j < 4; ++j) {
    o8[j]     = (short)f2bf(a[j] * rn);
    o8[j + 4] = (short)f2bf(b[j] * rn);
  }
  *(short8*)(xnq + (size_t)tok * C_ + lane * 8) = o8;
  if (lane == 0) {
    diff[tok]   = (ss - s * s * (1.f / C_)) * (1.f / (C_ - 1));  // ddof=1
    toksum[tok] = s;
  }
}

// ---- kernel 1b: per-head transposed bf16 V ---------------------------------
// xvT[bh][d] row of N ushorts, 64-key segments of 8 blocks; block lg (in
// order, NO physical XOR) holds keys 32*(lg>>2)+4*(lg&3)+16*(e>>2)+(e&3)
// (MFMA A k-slot order). k_attn applies its own slot XOR when staging.
__global__ __launch_bounds__(256) void k_transpose(
    const float* __restrict__ x, unsigned short* __restrict__ xvT) {
  __shared__ float tr[HD_][65];
  int bh = blockIdx.x & 15, nt = blockIdx.x >> 4;
  int b = bh >> 2, h = bh & 3;
  int n0 = nt * 64, c0 = h * HD_;
  int t = threadIdx.x;
  int dm = (t & 31) * 4;
  int nr = t >> 5;
#pragma unroll
  for (int p = 0; p < 8; ++p) {
    int n = p * 8 + nr;
    float4_t v = *(const float4_t*)(x + ((size_t)(b * N_ + n0 + n)) * C_ + c0 + dm);
#pragma unroll
    for (int k = 0; k < 4; ++k) tr[dm + k][n] = v[k];
  }
  __syncthreads();
#pragma unroll
  for (int p4 = 0; p4 < 4; ++p4) {
    int c = p4 * 256 + t;
    int d = c >> 3, lg = c & 7;
    int kbase = 32 * (lg >> 2) + 4 * (lg & 3);
    short8 o8;
#pragma unroll
    for (int e = 0; e < 8; ++e)
      o8[e] = (short)f2bf(tr[d][kbase + 16 * (e >> 2) + (e & 3)]);
    *(short8*)(xvT + ((size_t)(bh * HD_ + d)) * N_ + n0 + lg * 8) = o8;
  }
}

// ---- kernel 2: global diff mean/std + per-batch gate -----------------------
__global__ __launch_bounds__(256) void k_finalize(
    const float* __restrict__ diff, const float* __restrict__ toksum,
    const float* __restrict__ gw, const float* __restrict__ gb,
    float* __restrict__ stats) {
  __shared__ float sh[4][8];
  int t = threadIdx.x, l = t & 63, w = t >> 6;
  float s1 = 0.f, s2 = 0.f;
  for (int i = t; i < BN_; i += 256) { float d = diff[i]; s1 += d; s2 += d * d; }
  float bs0 = 0.f, bs1 = 0.f, bs2 = 0.f, bs3 = 0.f;
  for (int i = t; i < N_; i += 256) {
    bs0 += toksum[i];          bs1 += toksum[N_ + i];
    bs2 += toksum[2 * N_ + i]; bs3 += toksum[3 * N_ + i];
  }
#pragma unroll
  for (int o = 1; o < 64; o <<= 1) {
    s1 += __shfl_xor(s1, o);  s2 += __shfl_xor(s2, o);
    bs0 += __shfl_xor(bs0, o); bs1 += __shfl_xor(bs1, o);
    bs2 += __shfl_xor(bs2, o); bs3 += __shfl_xor(bs3, o);
  }
  if (l == 0) {
    sh[w][0] = s1; sh[w][1] = s2;
    sh[w][2] = bs0; sh[w][3] = bs1; sh[w][4] = bs2; sh[w][5] = bs3;
  }
  __syncthreads();
  if (t == 0) {
    float S1 = sh[0][0] + sh[1][0] + sh[2][0] + sh[3][0];
    float S2 = sh[0][1] + sh[1][1] + sh[2][1] + sh[3][1];
    float mean = S1 / (float)BN_;
    float var  = (S2 - S1 * S1 / (float)BN_) / (float)(BN_ - 1);
    float rstd = 1.f / (sqrtf(var) + 1e-6f);
    stats[0] = mean; stats[1] = rstd;
    float w00 = gw[0], bb = gb[0];
#pragma unroll
    for (int q = 0; q < 4; ++q) {
      float bsum = sh[0][2 + q] + sh[1][2 + q] + sh[2][2 + q] + sh[3][2 + q];
      float gi = bsum / (float)(N_ * C_);
      stats[2 + q] = 1.f / (1.f + __expf(-(gi * w00 + bb)));
    }
  }
}

// ---- kernel 3: fused flash attention + edge/gate epilogue ------------------
// R5-R8 lesson: the VGPR pool is 512/SIMD; an 8-wave (512-thr) block forces
// 2 waves/SIMD = 256 regs/wave (VGPR+AGPR unified) < demand ~290 -> the
// allocator spills ~35 regs/iter no matter what attributes say (R5-R8:
// 200-440 MB of scratch HBM traffic, 140-190us).  Fix: 4-wave (256-thr)
// block at 1 block/CU = 1 wave/SIMD = 512-reg budget (m08: no spill to 450).
// Block = (bh, 64-q tile); wave w = key-quarter [w*512, w*512+512), 32 keys
// per iter, NIT=16.  LDS 128 KB dynamic: K dbuf [0,64K), V dbuf [64K,128K),
// each 128-key tile = 4 x 32-key chunks (one per wave quarter).  Cross-wave
// O/ls reduction at the end.  grid 512 = 2 sequential rounds per CU.
__global__ __attribute__((amdgpu_flat_work_group_size(256, 256)))
__attribute__((amdgpu_waves_per_eu(1, 1))) void k_attn(
    const float* __restrict__ x, const unsigned short* __restrict__ xnq,
    const unsigned short* __restrict__ xvT, const float* __restrict__ diff,
    const float* __restrict__ stats, float* __restrict__ out) {
  extern __shared__ unsigned char smraw[];
  int i  = blockIdx.x;
  int bh = ((i & 7) << 1) | ((i >> 3) & 1);   // XCD-affine: 2 heads per XCD
  int qt = i >> 4;                            // 0..31
  int b = bh >> 2, h = bh & 3, c0 = h * HD_;
  int tid = threadIdx.x, w = tid >> 6, l = tid & 63;
  int g = l >> 4, r = l & 15;
  int q0 = qt * 64;

  // Q fragments: 4 q-subtiles x 4 channel-slices (B-operand), 64 VGPRs
  short8 qf[4][4];
  const unsigned short* qbase = xnq + ((size_t)(b * N_ + q0)) * C_ + c0;
#pragma unroll
  for (int qs = 0; qs < 4; ++qs)
#pragma unroll
    for (int cs = 0; cs < 4; ++cs)
      qf[qs][cs] = *(const short8*)(qbase + (size_t)(qs * 16 + r) * C_ + cs * 32 + g * 8);

  // staging source offsets (ushort elements), advanced incrementally
  uint32_t koff[8], voff[8];
  const unsigned short* kqbase = xnq + (size_t)b * N_ * C_ + c0;
  const unsigned short* vgbase = xvT + (size_t)bh * HD_ * N_;
#pragma unroll
  for (int jj = 0; jj < 8; ++jj) {
    int j   = w * 8 + jj;
    int row = 4 * j + (l >> 4);
    int cb  = (l & 15) ^ (row & 15);
    koff[jj] = (uint32_t)(((row >> 5) * 512 + (row & 31)) * C_ + cb * 8);
    int d   = row;
    int ksg = (l & 15) ^ (d & 15);
    voff[jj] = (uint32_t)(d * N_ + (ksg >> 2) * 512 + (ksg & 3) * 8);
  }

  // LDS read bases (byte offsets into smraw); wave reads its own quarter only
  int kaddr[4];
#pragma unroll
  for (int cs = 0; cs < 4; ++cs)
    kaddr[cs] = (w * 32 + r) * 256 + (((g + cs * 4) ^ r) * 16);
  int vaddr = 65536 + r * 256 + (((w * 4 + g) ^ r) * 16);

  float4_t acc[8][4];
  float ls[4] = {0.f, 0.f, 0.f, 0.f};
#pragma unroll
  for (int dt = 0; dt < 8; ++dt)
#pragma unroll
    for (int qs = 0; qs < 4; ++qs) acc[dt][qs] = (float4_t){0.f, 0.f, 0.f, 0.f};

  auto stage = [&](int cb) {
#pragma unroll
    for (int jj = 0; jj < 8; ++jj)
      GLOAD16(kqbase + koff[jj], smraw + cb * 32768 + (w * 8 + jj) * 1024);
#pragma unroll
    for (int jj = 0; jj < 8; ++jj)
      GLOAD16(vgbase + voff[jj], smraw + 65536 + cb * 32768 + (w * 8 + jj) * 1024);
  };
  auto advance = [&]() {
#pragma unroll
    for (int jj = 0; jj < 8; ++jj) { koff[jj] += 32 * C_; voff[jj] += 32; }
  };

  stage(0);
  advance();
  __syncthreads();

#pragma unroll 2
  for (int it = 0; it < NIT_; ++it) {
    int cb = it & 1;
    if (it + 1 < NIT_) { stage(cb ^ 1); advance(); }

    const char* smb = (const char*)smraw;
    union { short8 s8; uint32_t u[4]; } pfq[4];

    // QK^T + softmax, phased per 16-key subtile ks2
#pragma unroll
    for (int ks2 = 0; ks2 < 2; ++ks2) {
      short8 kf[4];
#pragma unroll
      for (int cs = 0; cs < 4; ++cs)
        kf[cs] = *(const short8*)(smb + cb * 32768 + ks2 * 4096 + kaddr[cs]);
      __builtin_amdgcn_s_setprio(1);
#pragma unroll
      for (int qs = 0; qs < 4; ++qs) {
        float4_t p = (float4_t){0.f, 0.f, 0.f, 0.f};
#pragma unroll
        for (int cs = 0; cs < 4; ++cs)
          p = mfma16(kf[cs], qf[qs][cs], p);
        float e0 = EXP2(p[0] * SCALE_LOG2E);
        float e1 = EXP2(p[1] * SCALE_LOG2E);
        float e2 = EXP2(p[2] * SCALE_LOG2E);
        float e3 = EXP2(p[3] * SCALE_LOG2E);
        ls[qs] += (e0 + e1) + (e2 + e3);
        pfq[qs].u[ks2 * 2 + 0] = cvtpk_bf16(e0, e1);
        pfq[qs].u[ks2 * 2 + 1] = cvtpk_bf16(e2, e3);
      }
      __builtin_amdgcn_s_setprio(0);
    }

    // PV: O^T += V^T(32-key slice) * P^T
    __builtin_amdgcn_s_setprio(1);
#pragma unroll
    for (int dt = 0; dt < 8; ++dt) {
      short8 vf = *(const short8*)(smb + cb * 32768 + dt * 4096 + vaddr);
#pragma unroll
      for (int qs = 0; qs < 4; ++qs)
        acc[dt][qs] = mfma16(vf, pfq[qs].s8, acc[dt][qs]);
    }
    __builtin_amdgcn_s_setprio(0);
    __syncthreads();
  }

  // ---- epilogue: ls cross-lane + cross-wave; O cross-wave in 4 dt-rounds --
#pragma unroll
  for (int qs = 0; qs < 4; ++qs) {
    ls[qs] += __shfl_xor(ls[qs], 16);
    ls[qs] += __shfl_xor(ls[qs], 32);
  }
  float* lsx = (float*)smraw;
  if (l < 16) {
#pragma unroll
    for (int qs = 0; qs < 4; ++qs) lsx[(w * 4 + qs) * 16 + l] = ls[qs];
  }
  __syncthreads();
  float lst[4];
#pragma unroll
  for (int qs = 0; qs < 4; ++qs)
    lst[qs] = lsx[(0 * 4 + qs) * 16 + r] + lsx[(1 * 4 + qs) * 16 + r] +
              lsx[(2 * 4 + qs) * 16 + r] + lsx[(3 * 4 + qs) * 16 + r];

  float mean = stats[0], rstd = stats[1], gate = stats[2 + b];
  float fq[4];
#pragma unroll
  for (int qs = 0; qs < 4; ++qs) {
    int q = q0 + qs * 16 + r;
    float dv = diff[b * N_ + q];
    float em = 1.f / (1.f + __expf(-(dv - mean) * rstd));
    fq[qs] = gate * (1.f + 0.5f * em) / lst[qs];
  }

  float4_t* ex = (float4_t*)(smraw + 4096);
#pragma unroll
  for (int rr = 0; rr < 4; ++rr) {
    __syncthreads();
#pragma unroll
    for (int dd = 0; dd < 2; ++dd)
#pragma unroll
      for (int qs = 0; qs < 4; ++qs)
        ex[((w * 2 + dd) * 4 + qs) * 64 + l] = acc[rr * 2 + dd][qs];
    __syncthreads();
    if (w == rr) {
#pragma unroll
      for (int dd = 0; dd < 2; ++dd) {
        int dt = rr * 2 + dd;
#pragma unroll
        for (int qs = 0; qs < 4; ++qs) {
          float4_t sum = ex[((0 * 2 + dd) * 4 + qs) * 64 + l];
#pragma unroll
          for (int k2 = 1; k2 < 4; ++k2) {
            float4_t o = ex[((k2 * 2 + dd) * 4 + qs) * 64 + l];
#pragma unroll
            for (int j = 0; j < 4; ++j) sum[j] += o[j];
          }
          int q = q0 + qs * 16 + r;
          int dcol = c0 + dt * 16 + g * 4;   // C/D: row = 4g+j, col = r
          const float* xr2 = x + ((size_t)(b * N_ + q)) * C_ + dcol;
          float* orow = out + ((size_t)(b * N_ + q)) * C_ + dcol;
          float4_t xin = *(const float4_t*)xr2;
          float4_t o;
#pragma unroll
          for (int j = 0; j < 4; ++j) o[j] = xin[j] + fq[qs] * sum[j];
          *(float4_t*)orow = o;
        }
      }
    }
  }
}

extern "C" void kernel_launch(void* const* d_in, const int* in_sizes, int n_in,
                              void* d_out, int out_size, void* d_ws, size_t ws_size,
                              hipStream_t stream) {
  (void)in_sizes; (void)n_in; (void)out_size; (void)ws_size;
  const float* x  = (const float*)d_in[0];
  const float* gw = (const float*)d_in[1];
  const float* gb = (const float*)d_in[2];
  float* out = (float*)d_out;
  // ws layout: xnq bf16 [8192][512] | xvT bf16 [16][128][2048] | diff | toksum | stats
  unsigned short* xnq = (unsigned short*)d_ws;
  unsigned short* xvT = xnq + (size_t)BN_ * C_;
  float* diff   = (float*)(xvT + (size_t)BN_ * C_);
  float* toksum = diff + BN_;
  float* stats  = toksum + BN_;
  hipFuncSetAttribute((const void*)k_attn,
                      hipFuncAttributeMaxDynamicSharedMemorySize, 131072);
  hipLaunchKernelGGL(k_stats, dim3(BN_ / 4), dim3(256), 0, stream, x, xnq, diff, toksum);
  hipLaunchKernelGGL(k_transpose, dim3(512), dim3(256), 0, stream, x, xvT);
  hipLaunchKernelGGL(k_finalize, dim3(1), dim3(256), 0, stream, diff, toksum, gw, gb, stats);
  hipLaunchKernelGGL(k_attn, dim3(512), dim3(256), 131072, stream,
                     x, xnq, xvT, diff, stats, out);
}

// Round 11
// 72.789 us; speedup vs baseline: 2.9375x; 1.3015x over previous
//
#include <hip/hip_runtime.h>
#include <stdint.h>

#define B_   4
#define N_   2048
#define C_   512
#define H_   4
#define HD_  128
#define BN_  (B_ * N_)
#define NIT_ 16
// exp(s/sqrt(128)) == exp2(s * SCALE_LOG2E)
#define SCALE_LOG2E 0.1275129727595311f

typedef __attribute__((ext_vector_type(8))) short  short8;
typedef __attribute__((ext_vector_type(4))) float  float4_t;
typedef __attribute__((ext_vector_type(8))) __bf16 bf16x8;

static __device__ __forceinline__ unsigned short f2bf(float f) {
  union { float f; uint32_t u; } v; v.f = f;
  uint32_t r = v.u + 0x7FFFu + ((v.u >> 16) & 1u);
  return (unsigned short)(r >> 16);
}

static __device__ __forceinline__ uint32_t cvtpk_bf16(float lo, float hi) {
  uint32_t r;
  asm("v_cvt_pk_bf16_f32 %0, %1, %2" : "=v"(r) : "v"(lo), "v"(hi));
  return r;
}

#if __has_builtin(__builtin_amdgcn_exp2f)
#define EXP2(x) __builtin_amdgcn_exp2f(x)
#else
#define EXP2(x) exp2f(x)
#endif

static __device__ __forceinline__ float4_t mfma16(short8 a, short8 b, float4_t c) {
  return __builtin_amdgcn_mfma_f32_16x16x32_bf16(
      __builtin_bit_cast(bf16x8, a), __builtin_bit_cast(bf16x8, b), c, 0, 0, 0);
}

#define GLOAD16(SRC, DST)                                               \
  __builtin_amdgcn_global_load_lds(                                     \
      (const __attribute__((address_space(1))) void*)(SRC),             \
      (__attribute__((address_space(3))) void*)(DST), 16, 0, 0)

// ---- kernel 1: per-token norm/var/sum + normalized bf16 x ------------------
__global__ __launch_bounds__(256) void k_stats(
    const float* __restrict__ x, unsigned short* __restrict__ xnq,
    float* __restrict__ diff, float* __restrict__ toksum) {
  int tok  = blockIdx.x * 4 + (threadIdx.x >> 6);
  int lane = threadIdx.x & 63;
  const float* xr = x + (size_t)tok * C_;
  float4_t a = *(const float4_t*)(xr + lane * 8);
  float4_t b = *(const float4_t*)(xr + lane * 8 + 4);
  float s = 0.f, ss = 0.f;
#pragma unroll
  for (int j = 0; j < 4; ++j) {
    s  += a[j] + b[j];
    ss += a[j] * a[j] + b[j] * b[j];
  }
#pragma unroll
  for (int o = 1; o < 64; o <<= 1) {
    s  += __shfl_xor(s, o);
    ss += __shfl_xor(ss, o);
  }
  float rn = 1.f / fmaxf(sqrtf(ss), 1e-12f);
  short8 o8;
#pragma unroll
  for (int j = 0; j < 4; ++j) {
    o8[j]     = (short)f2bf(a[j] * rn);
    o8[j + 4] = (short)f2bf(b[j] * rn);
  }
  *(short8*)(xnq + (size_t)tok * C_ + lane * 8) = o8;
  if (lane == 0) {
    diff[tok]   = (ss - s * s * (1.f / C_)) * (1.f / (C_ - 1));  // ddof=1
    toksum[tok] = s;
  }
}

// ---- kernel 1b: per-head transposed bf16 V ---------------------------------
// xvT[bh][d] row of N ushorts, 64-key segments of 8 blocks; block lg holds
// keys 32*(lg>>2)+4*(lg&3)+16*(e>>2)+(e&3) (MFMA A k-slot order).
__global__ __launch_bounds__(256) void k_transpose(
    const float* __restrict__ x, unsigned short* __restrict__ xvT) {
  __shared__ float tr[HD_][65];
  int bh = blockIdx.x & 15, nt = blockIdx.x >> 4;
  int b = bh >> 2, h = bh & 3;
  int n0 = nt * 64, c0 = h * HD_;
  int t = threadIdx.x;
  int dm = (t & 31) * 4;
  int nr = t >> 5;
#pragma unroll
  for (int p = 0; p < 8; ++p) {
    int n = p * 8 + nr;
    float4_t v = *(const float4_t*)(x + ((size_t)(b * N_ + n0 + n)) * C_ + c0 + dm);
#pragma unroll
    for (int k = 0; k < 4; ++k) tr[dm + k][n] = v[k];
  }
  __syncthreads();
#pragma unroll
  for (int p4 = 0; p4 < 4; ++p4) {
    int c = p4 * 256 + t;
    int d = c >> 3, lg = c & 7;
    int kbase = 32 * (lg >> 2) + 4 * (lg & 3);
    short8 o8;
#pragma unroll
    for (int e = 0; e < 8; ++e)
      o8[e] = (short)f2bf(tr[d][kbase + 16 * (e >> 2) + (e & 3)]);
    *(short8*)(xvT + ((size_t)(bh * HD_ + d)) * N_ + n0 + lg * 8) = o8;
  }
}

// ---- kernel 2: global diff mean/std + per-batch gate -----------------------
__global__ __launch_bounds__(256) void k_finalize(
    const float* __restrict__ diff, const float* __restrict__ toksum,
    const float* __restrict__ gw, const float* __restrict__ gb,
    float* __restrict__ stats) {
  __shared__ float sh[4][8];
  int t = threadIdx.x, l = t & 63, w = t >> 6;
  float s1 = 0.f, s2 = 0.f;
  for (int i = t; i < BN_; i += 256) { float d = diff[i]; s1 += d; s2 += d * d; }
  float bs0 = 0.f, bs1 = 0.f, bs2 = 0.f, bs3 = 0.f;
  for (int i = t; i < N_; i += 256) {
    bs0 += toksum[i];          bs1 += toksum[N_ + i];
    bs2 += toksum[2 * N_ + i]; bs3 += toksum[3 * N_ + i];
  }
#pragma unroll
  for (int o = 1; o < 64; o <<= 1) {
    s1 += __shfl_xor(s1, o);  s2 += __shfl_xor(s2, o);
    bs0 += __shfl_xor(bs0, o); bs1 += __shfl_xor(bs1, o);
    bs2 += __shfl_xor(bs2, o); bs3 += __shfl_xor(bs3, o);
  }
  if (l == 0) {
    sh[w][0] = s1; sh[w][1] = s2;
    sh[w][2] = bs0; sh[w][3] = bs1; sh[w][4] = bs2; sh[w][5] = bs3;
  }
  __syncthreads();
  if (t == 0) {
    float S1 = sh[0][0] + sh[1][0] + sh[2][0] + sh[3][0];
    float S2 = sh[0][1] + sh[1][1] + sh[2][1] + sh[3][1];
    float mean = S1 / (float)BN_;
    float var  = (S2 - S1 * S1 / (float)BN_) / (float)(BN_ - 1);
    float rstd = 1.f / (sqrtf(var) + 1e-6f);
    stats[0] = mean; stats[1] = rstd;
    float w00 = gw[0], bb = gb[0];
#pragma unroll
    for (int q = 0; q < 4; ++q) {
      float bsum = sh[0][2 + q] + sh[1][2 + q] + sh[2][2 + q] + sh[3][2 + q];
      float gi = bsum / (float)(N_ * C_);
      stats[2 + q] = 1.f / (1.f + __expf(-(gi * w00 + bb)));
    }
  }
}

// ---- kernel 3: fused flash attention + edge/gate epilogue ------------------
// grid 256 (1 block/CU) x 512 thr (8 waves = 2 waves/SIMD -> TLP).
// Reg budget at 2 waves/SIMD = 256/wave (VGPR+AGPR unified; 512-reg pool per
// SIMD).  R5-R8 spilled (demand ~290); R9 proved 1 wave/SIMD kills TLP (74us
// at 22% of MFMA floor).  This version keeps R8's math (passed 4x) but diets
// registers to ~250: no unroll-2 (was double-buffering kf/pfq copies),
// wave-uniform values in SGPRs, staging advance via uniform pointer bumps.
__global__ __launch_bounds__(512) void k_attn(
    const float* __restrict__ x, const unsigned short* __restrict__ xnq,
    const unsigned short* __restrict__ xvT, const float* __restrict__ diff,
    const float* __restrict__ stats, float* __restrict__ out) {
  extern __shared__ unsigned char smraw[];
  int i  = blockIdx.x;
  int bh = ((i & 7) << 1) | ((i >> 3) & 1);   // XCD-affine
  int qt = i >> 4;
  int b = bh >> 2, h = bh & 3, c0 = h * HD_;
  int tid = threadIdx.x;
  int w = __builtin_amdgcn_readfirstlane(tid >> 6);  // wave id -> SGPR
  int l = tid & 63;
  int ks = w & 3, qh = w >> 2;
  int g = l >> 4, r = l & 15;
  int q0 = qt * 128 + qh * 64;

  // Q fragments: 4 q-subtiles x 4 channel-slices (B-operand), 64 VGPRs
  short8 qf[4][4];
  const unsigned short* qbase = xnq + ((size_t)(b * N_ + q0)) * C_ + c0;
#pragma unroll
  for (int qs = 0; qs < 4; ++qs)
#pragma unroll
    for (int cs = 0; cs < 4; ++cs)
      qf[qs][cs] = *(const short8*)(qbase + (size_t)(qs * 16 + r) * C_ + cs * 32 + g * 8);

  // per-lane staging offsets (ushort elements), iteration-invariant
  uint32_t koff[4], voff[4];
#pragma unroll
  for (int jj = 0; jj < 4; ++jj) {
    int j   = w * 4 + jj;
    int row = 4 * j + (l >> 4);
    int cb2 = (l & 15) ^ (row & 15);
    koff[jj] = (uint32_t)(((row >> 5) * 512 + (row & 31)) * C_ + cb2 * 8);
    int d   = row;
    int ksg = (l & 15) ^ (d & 15);
    voff[jj] = (uint32_t)(d * N_ + (ksg >> 2) * 512 + (ksg & 3) * 8);
  }

  // LDS read bases (byte offsets into smraw)
  int kaddr[4];
#pragma unroll
  for (int cs = 0; cs < 4; ++cs)
    kaddr[cs] = (ks * 32 + r) * 256 + (((g + cs * 4) ^ r) * 16);
  int vaddr = 65536 + r * 256 + (((ks * 4 + g) ^ r) * 16);

  float4_t acc[8][4];
  float ls[4] = {0.f, 0.f, 0.f, 0.f};
#pragma unroll
  for (int dt = 0; dt < 8; ++dt)
#pragma unroll
    for (int qs = 0; qs < 4; ++qs) acc[dt][qs] = (float4_t){0.f, 0.f, 0.f, 0.f};

  // iteration-scalar source pointers (advance by uniform stride each iter)
  const unsigned short* kq_it = xnq + (size_t)b * N_ * C_ + c0;
  const unsigned short* vg_it = xvT + (size_t)bh * HD_ * N_;

  auto stage = [&](const unsigned short* kq, const unsigned short* vg, int cb) {
#pragma unroll
    for (int jj = 0; jj < 4; ++jj)
      GLOAD16(kq + koff[jj], smraw + cb * 32768 + (w * 4 + jj) * 1024);
#pragma unroll
    for (int jj = 0; jj < 4; ++jj)
      GLOAD16(vg + voff[jj], smraw + 65536 + cb * 32768 + (w * 4 + jj) * 1024);
  };

  stage(kq_it, vg_it, 0);
  __syncthreads();

  for (int it = 0; it < NIT_; ++it) {
    int cb = it & 1;
    if (it + 1 < NIT_)
      stage(kq_it + (size_t)(it + 1) * 32 * C_, vg_it + (it + 1) * 32, cb ^ 1);

    const char* smb = (const char*)smraw + cb * 32768;
    union { short8 s8; uint32_t u[4]; } pfq[4];

    // QK^T + softmax, phased per 16-key subtile ks2 (minimal live set)
#pragma unroll
    for (int ks2 = 0; ks2 < 2; ++ks2) {
      short8 kf[4];
#pragma unroll
      for (int cs = 0; cs < 4; ++cs)
        kf[cs] = *(const short8*)(smb + ks2 * 4096 + kaddr[cs]);
      __builtin_amdgcn_s_setprio(1);
#pragma unroll
      for (int qs = 0; qs < 4; ++qs) {
        float4_t p = (float4_t){0.f, 0.f, 0.f, 0.f};
#pragma unroll
        for (int cs = 0; cs < 4; ++cs)
          p = mfma16(kf[cs], qf[qs][cs], p);
        float e0 = EXP2(p[0] * SCALE_LOG2E);
        float e1 = EXP2(p[1] * SCALE_LOG2E);
        float e2 = EXP2(p[2] * SCALE_LOG2E);
        float e3 = EXP2(p[3] * SCALE_LOG2E);
        ls[qs] += (e0 + e1) + (e2 + e3);
        pfq[qs].u[ks2 * 2 + 0] = cvtpk_bf16(e0, e1);
        pfq[qs].u[ks2 * 2 + 1] = cvtpk_bf16(e2, e3);
      }
      __builtin_amdgcn_s_setprio(0);
    }

    // PV: O^T += V^T(32-key slice) * P^T
    __builtin_amdgcn_s_setprio(1);
#pragma unroll
    for (int dt = 0; dt < 8; ++dt) {
      short8 vf = *(const short8*)(smb + dt * 4096 + vaddr);
#pragma unroll
      for (int qs = 0; qs < 4; ++qs)
        acc[dt][qs] = mfma16(vf, pfq[qs].s8, acc[dt][qs]);
    }
    __builtin_amdgcn_s_setprio(0);
    __syncthreads();
  }

  // ---- epilogue: ls cross-lane + cross-ks; O cross-ks in 4 dt-rounds ------
#pragma unroll
  for (int qs = 0; qs < 4; ++qs) {
    ls[qs] += __shfl_xor(ls[qs], 16);
    ls[qs] += __shfl_xor(ls[qs], 32);
  }
  float* lsx = (float*)smraw;
  if (l < 16) {
#pragma unroll
    for (int qs = 0; qs < 4; ++qs) lsx[(w * 4 + qs) * 16 + l] = ls[qs];
  }
  __syncthreads();
  float lst[4];
#pragma unroll
  for (int qs = 0; qs < 4; ++qs)
    lst[qs] = lsx[((qh * 4 + 0) * 4 + qs) * 16 + r] + lsx[((qh * 4 + 1) * 4 + qs) * 16 + r] +
              lsx[((qh * 4 + 2) * 4 + qs) * 16 + r] + lsx[((qh * 4 + 3) * 4 + qs) * 16 + r];

  float mean = stats[0], rstd = stats[1], gate = stats[2 + b];
  float fq[4];
#pragma unroll
  for (int qs = 0; qs < 4; ++qs) {
    int q = q0 + qs * 16 + r;
    float dv = diff[b * N_ + q];
    float em = 1.f / (1.f + __expf(-(dv - mean) * rstd));
    fq[qs] = gate * (1.f + 0.5f * em) / lst[qs];
  }

  float4_t* ex = (float4_t*)(smraw + 4096);
#pragma unroll
  for (int rr = 0; rr < 4; ++rr) {
    __syncthreads();
#pragma unroll
    for (int dd = 0; dd < 2; ++dd)
#pragma unroll
      for (int qs = 0; qs < 4; ++qs)
        ex[((w * 2 + dd) * 4 + qs) * 64 + l] = acc[rr * 2 + dd][qs];
    __syncthreads();
    if (ks == rr) {
#pragma unroll
      for (int dd = 0; dd < 2; ++dd) {
        int dt = rr * 2 + dd;
#pragma unroll
        for (int qs = 0; qs < 4; ++qs) {
          float4_t sum = ex[(((qh * 4 + 0) * 2 + dd) * 4 + qs) * 64 + l];
#pragma unroll
          for (int k2 = 1; k2 < 4; ++k2) {
            float4_t o = ex[(((qh * 4 + k2) * 2 + dd) * 4 + qs) * 64 + l];
#pragma unroll
            for (int j = 0; j < 4; ++j) sum[j] += o[j];
          }
          int q = q0 + qs * 16 + r;
          int dcol = c0 + dt * 16 + g * 4;   // C/D: row = 4g+j, col = r
          const float* xr2 = x + ((size_t)(b * N_ + q)) * C_ + dcol;
          float* orow = out + ((size_t)(b * N_ + q)) * C_ + dcol;
          float4_t xin = *(const float4_t*)xr2;
          float4_t o;
#pragma unroll
          for (int j = 0; j < 4; ++j) o[j] = xin[j] + fq[qs] * sum[j];
          *(float4_t*)orow = o;
        }
      }
    }
  }
}

extern "C" void kernel_launch(void* const* d_in, const int* in_sizes, int n_in,
                              void* d_out, int out_size, void* d_ws, size_t ws_size,
                              hipStream_t stream) {
  (void)in_sizes; (void)n_in; (void)out_size; (void)ws_size;
  const float* x  = (const float*)d_in[0];
  const float* gw = (const float*)d_in[1];
  const float* gb = (const float*)d_in[2];
  float* out = (float*)d_out;
  // ws layout: xnq bf16 [8192][512] | xvT bf16 [16][128][2048] | diff | toksum | stats
  unsigned short* xnq = (unsigned short*)d_ws;
  unsigned short* xvT = xnq + (size_t)BN_ * C_;
  float* diff   = (float*)(xvT + (size_t)BN_ * C_);
  float* toksum = diff + BN_;
  float* stats  = toksum + BN_;
  hipFuncSetAttribute((const void*)k_attn,
                      hipFuncAttributeMaxDynamicSharedMemorySize, 131072);
  hipLaunchKernelGGL(k_stats, dim3(BN_ / 4), dim3(256), 0, stream, x, xnq, diff, toksum);
  hipLaunchKernelGGL(k_transpose, dim3(512), dim3(256), 0, stream, x, xvT);
  hipLaunchKernelGGL(k_finalize, dim3(1), dim3(256), 0, stream, diff, toksum, gw, gb, stats);
  hipLaunchKernelGGL(k_attn, dim3(256), dim3(512), 131072, stream,
                     x, xnq, xvT, diff, stats, out);
}